// Round 8
// baseline (1258.472 us; speedup 1.0000x reference)
//
#include <hip/hip_runtime.h>
#include <hip/hip_fp16.h>

#define NN 50000
#define NE 800000
#define D  128
#define NG 8                   // sub-counters per node (XCD-affinity groups)
#define NC (NN * NG)           // 400000 sub-counters

// ---- main-path ws layout (bytes) ----
#define OFF_CNT8 0             // cnt8  int[NC]          1.6 MB
#define OFF_ROW8 1600512       // row8  int[NC+1]        1.6 MB
#define OFF_CUR8 3201536       // cur8  int[NC]          1.6 MB
#define OFF_CSR4 4802560       // csr4  uint[2E]         6.4 MB
#define OFF_XW   11202560      // XW bf16 ushort[NN*D]  12.8 MB
#define NEED_A   (OFF_XW + (size_t)NN * D * 2)   // ~24.0 MB

// ---- fallback ws layout ----
#define OFF_CNT  0
#define OFF_ROW  200704
#define OFF_CUR  401408
#define OFF_CSR8 602112        // int2[2E] 12.8 MB

__device__ __forceinline__ float bf_lo(unsigned int v) { return __uint_as_float(v << 16); }
__device__ __forceinline__ float bf_hi(unsigned int v) { return __uint_as_float(v & 0xffff0000u); }
__device__ __forceinline__ float wdec(unsigned int v) {
    return __half2float(__ushort_as_half((unsigned short)(v >> 16)));
}

// K1: per-edge histogram into per-(node, group) sub-counters. g = blockIdx&7
// so each sub-counter (and later its CSR sub-range) is touched by one XCD.
__global__ __launch_bounds__(256) void gc_hist8(
    const int2* __restrict__ edges, int* __restrict__ cnt8)
{
    int e = blockIdx.x * 256 + threadIdx.x;
    if (e >= NE) return;
    int g = blockIdx.x & (NG - 1);
    int2 p = edges[e];
    atomicAdd(cnt8 + p.x * NG + g, 1);
    atomicAdd(cnt8 + p.y * NG + g, 1);
}

// K2: single-block exclusive scan over 400K sub-counters -> row8, cur8
__global__ __launch_bounds__(1024) void gc_scan8(
    const int* __restrict__ cnt8, int* __restrict__ row8,
    int* __restrict__ cur8)
{
    const int CHUNK = (NC + 1023) / 1024;   // 391
    __shared__ int part[1024];
    int t = threadIdx.x;
    int lo = t * CHUNK, hi = min(lo + CHUNK, NC);
    int s = 0;
    for (int i = lo; i < hi; ++i) s += cnt8[i];
    part[t] = s;
    __syncthreads();
    for (int off = 1; off < 1024; off <<= 1) {
        int v = (t >= off) ? part[t - off] : 0;
        __syncthreads();
        part[t] += v;
        __syncthreads();
    }
    int run = part[t] - s;                  // exclusive prefix
    for (int i = lo; i < hi; ++i) {
        int c = cnt8[i];
        row8[i] = run;
        cur8[i] = run;
        run += c;
    }
    if (t == 1023) row8[NC] = part[1023];
}

// K3: fill 4-byte CSR entries (col:16 | w_fp16:16). Same g = blockIdx&7 as
// hist8, so all writes to a (node,g) sub-range come from one XCD -> the
// cacheline stays resident and writebacks merge.
__global__ __launch_bounds__(256) void gc_fill4(
    const int2* __restrict__ edges, const float* __restrict__ wts,
    int* __restrict__ cur8, unsigned int* __restrict__ csr4)
{
    int e = blockIdx.x * 256 + threadIdx.x;
    if (e >= NE) return;
    int g = blockIdx.x & (NG - 1);
    int2 p = edges[e];
    unsigned int hb = (unsigned int)__half_as_ushort(__float2half_rn(wts[e])) << 16;
    int pos = atomicAdd(cur8 + p.y * NG + g, 1);
    csr4[pos] = (unsigned int)p.x | hb;
    pos = atomicAdd(cur8 + p.x * NG + g, 1);
    csr4[pos] = (unsigned int)p.y | hb;
}

// K4: XW = X @ W, bf16 RNE output (packed). Block owns 16 rows; W in LDS.
__global__ __launch_bounds__(256) void gc_gemm_bf16(
    const float* __restrict__ src, unsigned short* __restrict__ dst,
    const float* __restrict__ Wm)
{
    __shared__ float Ws[D * D];
    __shared__ float axs[16 * D];
    const int tid = threadIdx.x;
    const int col = tid & 127;
    const int ty  = tid >> 7;
    const int rbase = blockIdx.x * 16;

    const float4* W4  = reinterpret_cast<const float4*>(Wm);
    float4*       Ws4 = reinterpret_cast<float4*>(Ws);
    #pragma unroll
    for (int i = 0; i < 16; ++i) Ws4[tid + i * 256] = W4[tid + i * 256];

    const float4* A4   = reinterpret_cast<const float4*>(src + (size_t)rbase * D);
    float4*       axs4 = reinterpret_cast<float4*>(axs);
    #pragma unroll
    for (int i = 0; i < 2; ++i) axs4[tid + i * 256] = A4[tid + i * 256];
    __syncthreads();

    float acc[8];
    #pragma unroll
    for (int i = 0; i < 8; ++i) acc[i] = 0.f;

    for (int k = 0; k < D; ++k) {
        float wv = Ws[k * D + col];
        #pragma unroll
        for (int i = 0; i < 8; ++i)
            acc[i] = fmaf(axs[(ty * 8 + i) * D + k], wv, acc[i]);
    }

    #pragma unroll
    for (int i = 0; i < 8; ++i) {
        unsigned int bb = __float_as_uint(acc[i]);
        unsigned int r  = (bb + 0x7fffu + ((bb >> 16) & 1u)) >> 16;   // RNE
        dst[(size_t)(rbase + ty * 8 + i) * D + col] = (unsigned short)r;
    }
}

// K5: gather bf16 rows, fused degree + normalization -> out (final).
__global__ __launch_bounds__(256) void gc_gather4(
    const int* __restrict__ row8, const unsigned int* __restrict__ csr4,
    const unsigned int* __restrict__ F, float* __restrict__ out)
{
    int wid  = (blockIdx.x * 256 + threadIdx.x) >> 6;
    int lane = threadIdx.x & 63;
    if (wid >= NN) return;
    int j   = row8[wid * NG];
    int end = row8[wid * NG + NG];          // == start of next node's row
    float ax = 0.f, ay = 0.f, dw = 0.f;
    for (; j + 4 <= end; j += 4) {
        unsigned int e0 = csr4[j], e1 = csr4[j + 1];
        unsigned int e2 = csr4[j + 2], e3 = csr4[j + 3];
        unsigned int v0 = F[(size_t)(e0 & 0xffffu) * 64 + lane];
        unsigned int v1 = F[(size_t)(e1 & 0xffffu) * 64 + lane];
        unsigned int v2 = F[(size_t)(e2 & 0xffffu) * 64 + lane];
        unsigned int v3 = F[(size_t)(e3 & 0xffffu) * 64 + lane];
        float w0 = wdec(e0), w1 = wdec(e1), w2 = wdec(e2), w3 = wdec(e3);
        ax = fmaf(w0, bf_lo(v0), ax); ay = fmaf(w0, bf_hi(v0), ay);
        ax = fmaf(w1, bf_lo(v1), ax); ay = fmaf(w1, bf_hi(v1), ay);
        ax = fmaf(w2, bf_lo(v2), ax); ay = fmaf(w2, bf_hi(v2), ay);
        ax = fmaf(w3, bf_lo(v3), ax); ay = fmaf(w3, bf_hi(v3), ay);
        dw += w0 + w1 + w2 + w3;
    }
    for (; j < end; ++j) {
        unsigned int e0 = csr4[j];
        unsigned int v0 = F[(size_t)(e0 & 0xffffu) * 64 + lane];
        float w0 = wdec(e0);
        ax = fmaf(w0, bf_lo(v0), ax); ay = fmaf(w0, bf_hi(v0), ay);
        dw += w0;
    }
    float inv = dw > 0.f ? 1.f / dw : 0.f;
    float2 r; r.x = ax * inv; r.y = ay * inv;
    reinterpret_cast<float2*>(out)[(size_t)wid * 64 + lane] = r;
}

// ======================= fallback path (fp32, small ws) ====================
__global__ __launch_bounds__(256) void gc_hist(
    const int2* __restrict__ edges, int* __restrict__ counts)
{
    int e = blockIdx.x * 256 + threadIdx.x;
    if (e >= NE) return;
    int2 p = edges[e];
    atomicAdd(counts + p.x, 1);
    atomicAdd(counts + p.y, 1);
}

__global__ __launch_bounds__(1024) void gc_scan(
    const int* __restrict__ counts, int* __restrict__ row_start,
    int* __restrict__ cursor)
{
    const int CHUNK = (NN + 1023) / 1024;
    __shared__ int part[1024];
    int t = threadIdx.x;
    int lo = t * CHUNK, hi = min(lo + CHUNK, NN);
    int s = 0;
    for (int i = lo; i < hi; ++i) s += counts[i];
    part[t] = s;
    __syncthreads();
    for (int off = 1; off < 1024; off <<= 1) {
        int v = (t >= off) ? part[t - off] : 0;
        __syncthreads();
        part[t] += v;
        __syncthreads();
    }
    int run = part[t] - s;
    for (int i = lo; i < hi; ++i) {
        int c = counts[i];
        row_start[i] = run;
        cursor[i]    = run;
        run += c;
    }
    if (t == 1023) row_start[NN] = part[1023];
}

__global__ __launch_bounds__(256) void gc_fill8(
    const int2* __restrict__ edges, const float* __restrict__ wts,
    int* __restrict__ cursor, int2* __restrict__ csr)
{
    int e = blockIdx.x * 256 + threadIdx.x;
    if (e >= NE) return;
    int2 p = edges[e];
    int wb = __float_as_int(wts[e]);
    int pos = atomicAdd(cursor + p.y, 1);
    csr[pos] = make_int2(p.x, wb);
    pos = atomicAdd(cursor + p.x, 1);
    csr[pos] = make_int2(p.y, wb);
}

__global__ __launch_bounds__(256) void gc_gather_f32(
    const int* __restrict__ row_start, const int2* __restrict__ csr,
    const float* __restrict__ F, float* __restrict__ out)
{
    int wid  = (blockIdx.x * 256 + threadIdx.x) >> 6;
    int lane = threadIdx.x & 63;
    if (wid >= NN) return;
    int j   = row_start[wid];
    int end = row_start[wid + 1];
    const float2* F2 = reinterpret_cast<const float2*>(F);
    float ax = 0.f, ay = 0.f, dw = 0.f;
    for (; j < end; ++j) {
        int2  cw = csr[j];
        float w  = __int_as_float(cw.y);
        float2 xv = F2[(size_t)cw.x * 64 + lane];
        ax = fmaf(w, xv.x, ax);
        ay = fmaf(w, xv.y, ay);
        dw += w;
    }
    float inv = dw > 0.f ? 1.f / dw : 0.f;
    float2 r; r.x = ax * inv; r.y = ay * inv;
    reinterpret_cast<float2*>(out)[(size_t)wid * 64 + lane] = r;
}

__global__ __launch_bounds__(256) void gc_gemm_f32(
    const float* __restrict__ src, float* __restrict__ dst,
    const float* __restrict__ Wm)
{
    __shared__ float Ws[D * D];
    __shared__ float axs[16 * D];
    const int tid = threadIdx.x;
    const int col = tid & 127;
    const int ty  = tid >> 7;
    const int rbase = blockIdx.x * 16;

    const float4* W4  = reinterpret_cast<const float4*>(Wm);
    float4*       Ws4 = reinterpret_cast<float4*>(Ws);
    #pragma unroll
    for (int i = 0; i < 16; ++i) Ws4[tid + i * 256] = W4[tid + i * 256];

    const float4* A4   = reinterpret_cast<const float4*>(src + (size_t)rbase * D);
    float4*       axs4 = reinterpret_cast<float4*>(axs);
    #pragma unroll
    for (int i = 0; i < 2; ++i) axs4[tid + i * 256] = A4[tid + i * 256];
    __syncthreads();

    float acc[8];
    #pragma unroll
    for (int i = 0; i < 8; ++i) acc[i] = 0.f;

    for (int k = 0; k < D; ++k) {
        float wv = Ws[k * D + col];
        #pragma unroll
        for (int i = 0; i < 8; ++i)
            acc[i] = fmaf(axs[(ty * 8 + i) * D + k], wv, acc[i]);
    }

    #pragma unroll
    for (int i = 0; i < 8; ++i)
        dst[(size_t)(rbase + ty * 8 + i) * D + col] = acc[i];
}

extern "C" void kernel_launch(void* const* d_in, const int* in_sizes, int n_in,
                              void* d_out, int out_size, void* d_ws, size_t ws_size,
                              hipStream_t stream) {
    const float* X     = (const float*)d_in[0];
    const int2*  edges = (const int2*)d_in[1];
    const float* wts   = (const float*)d_in[2];
    const float* Wm    = (const float*)d_in[3];
    float* out = (float*)d_out;
    char*  ws  = (char*)d_ws;

    const int eblocks = (NE + 255) / 256;   // 3125

    if (ws_size >= NEED_A) {
        int* cnt8 = (int*)(ws + OFF_CNT8);
        int* row8 = (int*)(ws + OFF_ROW8);
        int* cur8 = (int*)(ws + OFF_CUR8);
        unsigned int*   csr4 = (unsigned int*)(ws + OFF_CSR4);
        unsigned short* xw   = (unsigned short*)(ws + OFF_XW);

        hipMemsetAsync(cnt8, 0, NC * sizeof(int), stream);
        gc_hist8<<<eblocks, 256, 0, stream>>>(edges, cnt8);
        gc_scan8<<<1, 1024, 0, stream>>>(cnt8, row8, cur8);
        gc_fill4<<<eblocks, 256, 0, stream>>>(edges, wts, cur8, csr4);
        gc_gemm_bf16<<<NN / 16, 256, 0, stream>>>(X, xw, Wm);
        gc_gather4<<<(NN * 64 + 255) / 256, 256, 0, stream>>>(
            row8, csr4, (const unsigned int*)xw, out);
    } else {
        int*  counts    = (int*) (ws + OFF_CNT);
        int*  row_start = (int*) (ws + OFF_ROW);
        int*  cursor    = (int*) (ws + OFF_CUR);
        int2* csr       = (int2*)(ws + OFF_CSR8);

        hipMemsetAsync(counts, 0, NN * sizeof(int), stream);
        gc_hist<<<eblocks, 256, 0, stream>>>(edges, counts);
        gc_scan<<<1, 1024, 0, stream>>>(counts, row_start, cursor);
        gc_fill8<<<eblocks, 256, 0, stream>>>(edges, wts, cursor, csr);
        gc_gather_f32<<<(NN * 64 + 255) / 256, 256, 0, stream>>>(row_start, csr, X, out);
        gc_gemm_f32<<<NN / 16, 256, 0, stream>>>(out, out, Wm);
    }
}

// Round 9
// 321.620 us; speedup vs baseline: 3.9129x; 3.9129x over previous
//
#include <hip/hip_runtime.h>
#include <hip/hip_fp16.h>

#define NN 50000
#define NE 800000
#define D  128
#define NG 8                   // sub-counters per node (XCD-affinity groups)
#define NC (NN * NG)           // 400000 sub-counters
#define SCB 1024               // elements per scan block
#define NSB ((NC + SCB - 1) / SCB)   // 391 scan blocks

// ---- main-path ws layout (bytes) ----
#define OFF_CNT8 0             // cnt8  int[NC]          1.6 MB
#define OFF_ROW8 1600512       // row8  int[NC+1]        1.6 MB
#define OFF_CUR8 3201536       // cur8  int[NC]          1.6 MB
#define OFF_BSUM 4802560       // bsum  int[NSB]         ~1.6 KB
#define OFF_CSR4 4804608       // csr4  uint[2E]         6.4 MB
#define OFF_XW   11204608      // XW bf16 ushort[NN*D]  12.8 MB
#define NEED_A   (OFF_XW + (size_t)NN * D * 2)   // ~24.0 MB

// ---- fallback ws layout ----
#define OFF_CNT  0
#define OFF_ROW  200704
#define OFF_CUR  401408
#define OFF_CSR8 602112        // int2[2E] 12.8 MB

__device__ __forceinline__ float bf_lo(unsigned int v) { return __uint_as_float(v << 16); }
__device__ __forceinline__ float bf_hi(unsigned int v) { return __uint_as_float(v & 0xffff0000u); }
__device__ __forceinline__ float wdec(unsigned int v) {
    return __half2float(__ushort_as_half((unsigned short)(v >> 16)));
}

// K1: per-edge histogram into per-(node, group) sub-counters. g = blockIdx&7
__global__ __launch_bounds__(256) void gc_hist8(
    const int2* __restrict__ edges, int* __restrict__ cnt8)
{
    int e = blockIdx.x * 256 + threadIdx.x;
    if (e >= NE) return;
    int g = blockIdx.x & (NG - 1);
    int2 p = edges[e];
    atomicAdd(cnt8 + p.x * NG + g, 1);
    atomicAdd(cnt8 + p.y * NG + g, 1);
}

// K2a: per-chunk partial sums (coalesced)
__global__ __launch_bounds__(256) void gc_scanA(
    const int* __restrict__ in, int* __restrict__ bsum)
{
    __shared__ int red[256];
    int base = blockIdx.x * SCB;
    int s = 0;
    for (int i = threadIdx.x; i < SCB; i += 256) {
        int idx = base + i;
        s += (idx < NC) ? in[idx] : 0;
    }
    red[threadIdx.x] = s;
    __syncthreads();
    for (int off = 128; off > 0; off >>= 1) {
        if (threadIdx.x < off) red[threadIdx.x] += red[threadIdx.x + off];
        __syncthreads();
    }
    if (threadIdx.x == 0) bsum[blockIdx.x] = red[0];
}

// K2b: single-block exclusive scan of NSB (<=1024) block sums, in place
__global__ __launch_bounds__(1024) void gc_scanB(int* __restrict__ bsum)
{
    __shared__ int part[1024];
    int t = threadIdx.x;
    int v = (t < NSB) ? bsum[t] : 0;
    part[t] = v;
    __syncthreads();
    for (int off = 1; off < 1024; off <<= 1) {
        int x = (t >= off) ? part[t - off] : 0;
        __syncthreads();
        part[t] += x;
        __syncthreads();
    }
    if (t < NSB) bsum[t] = part[t] - v;     // exclusive
}

// K2c: per-chunk local exclusive scan + block offset -> row8, cur8
__global__ __launch_bounds__(256) void gc_scanC(
    const int* __restrict__ in, const int* __restrict__ bsum,
    int* __restrict__ row8, int* __restrict__ cur8)
{
    __shared__ int part[256];
    int base = blockIdx.x * SCB;
    int idx0 = base + threadIdx.x * 4;
    int4 v = make_int4(0, 0, 0, 0);
    if (idx0 + 3 < NC) v = *reinterpret_cast<const int4*>(in + idx0);
    else {
        if (idx0 + 0 < NC) v.x = in[idx0 + 0];
        if (idx0 + 1 < NC) v.y = in[idx0 + 1];
        if (idx0 + 2 < NC) v.z = in[idx0 + 2];
        if (idx0 + 3 < NC) v.w = in[idx0 + 3];
    }
    int s = v.x + v.y + v.z + v.w;
    part[threadIdx.x] = s;
    __syncthreads();
    for (int off = 1; off < 256; off <<= 1) {
        int x = (threadIdx.x >= off) ? part[threadIdx.x - off] : 0;
        __syncthreads();
        part[threadIdx.x] += x;
        __syncthreads();
    }
    int run = bsum[blockIdx.x] + part[threadIdx.x] - s;
    int r0 = run, r1 = r0 + v.x, r2 = r1 + v.y, r3 = r2 + v.z;
    if (idx0 + 3 < NC) {
        *reinterpret_cast<int4*>(row8 + idx0) = make_int4(r0, r1, r2, r3);
        *reinterpret_cast<int4*>(cur8 + idx0) = make_int4(r0, r1, r2, r3);
    } else {
        if (idx0 + 0 < NC) { row8[idx0 + 0] = r0; cur8[idx0 + 0] = r0; }
        if (idx0 + 1 < NC) { row8[idx0 + 1] = r1; cur8[idx0 + 1] = r1; }
        if (idx0 + 2 < NC) { row8[idx0 + 2] = r2; cur8[idx0 + 2] = r2; }
        if (idx0 + 3 < NC) { row8[idx0 + 3] = r3; cur8[idx0 + 3] = r3; }
    }
    if (blockIdx.x == 0 && threadIdx.x == 0) row8[NC] = 2 * NE;  // static total
}

// K3: fill 4-byte CSR entries (col:16 | w_fp16:16), XCD-grouped cursors
__global__ __launch_bounds__(256) void gc_fill4(
    const int2* __restrict__ edges, const float* __restrict__ wts,
    int* __restrict__ cur8, unsigned int* __restrict__ csr4)
{
    int e = blockIdx.x * 256 + threadIdx.x;
    if (e >= NE) return;
    int g = blockIdx.x & (NG - 1);
    int2 p = edges[e];
    unsigned int hb = (unsigned int)__half_as_ushort(__float2half_rn(wts[e])) << 16;
    int pos = atomicAdd(cur8 + p.y * NG + g, 1);
    csr4[pos] = (unsigned int)p.x | hb;
    pos = atomicAdd(cur8 + p.x * NG + g, 1);
    csr4[pos] = (unsigned int)p.y | hb;
}

// K4: XW = X @ W, bf16 RNE output (packed)
__global__ __launch_bounds__(256) void gc_gemm_bf16(
    const float* __restrict__ src, unsigned short* __restrict__ dst,
    const float* __restrict__ Wm)
{
    __shared__ float Ws[D * D];
    __shared__ float axs[16 * D];
    const int tid = threadIdx.x;
    const int col = tid & 127;
    const int ty  = tid >> 7;
    const int rbase = blockIdx.x * 16;

    const float4* W4  = reinterpret_cast<const float4*>(Wm);
    float4*       Ws4 = reinterpret_cast<float4*>(Ws);
    #pragma unroll
    for (int i = 0; i < 16; ++i) Ws4[tid + i * 256] = W4[tid + i * 256];

    const float4* A4   = reinterpret_cast<const float4*>(src + (size_t)rbase * D);
    float4*       axs4 = reinterpret_cast<float4*>(axs);
    #pragma unroll
    for (int i = 0; i < 2; ++i) axs4[tid + i * 256] = A4[tid + i * 256];
    __syncthreads();

    float acc[8];
    #pragma unroll
    for (int i = 0; i < 8; ++i) acc[i] = 0.f;

    for (int k = 0; k < D; ++k) {
        float wv = Ws[k * D + col];
        #pragma unroll
        for (int i = 0; i < 8; ++i)
            acc[i] = fmaf(axs[(ty * 8 + i) * D + k], wv, acc[i]);
    }

    #pragma unroll
    for (int i = 0; i < 8; ++i) {
        unsigned int bb = __float_as_uint(acc[i]);
        unsigned int r  = (bb + 0x7fffu + ((bb >> 16) & 1u)) >> 16;   // RNE
        dst[(size_t)(rbase + ty * 8 + i) * D + col] = (unsigned short)r;
    }
}

// K5: gather bf16 rows, fused degree + normalization -> out (final)
__global__ __launch_bounds__(256) void gc_gather4(
    const int* __restrict__ row8, const unsigned int* __restrict__ csr4,
    const unsigned int* __restrict__ F, float* __restrict__ out)
{
    int wid  = (blockIdx.x * 256 + threadIdx.x) >> 6;
    int lane = threadIdx.x & 63;
    if (wid >= NN) return;
    int j   = row8[wid * NG];
    int end = row8[wid * NG + NG];
    float ax = 0.f, ay = 0.f, dw = 0.f;
    for (; j + 4 <= end; j += 4) {
        unsigned int e0 = csr4[j], e1 = csr4[j + 1];
        unsigned int e2 = csr4[j + 2], e3 = csr4[j + 3];
        unsigned int v0 = F[(size_t)(e0 & 0xffffu) * 64 + lane];
        unsigned int v1 = F[(size_t)(e1 & 0xffffu) * 64 + lane];
        unsigned int v2 = F[(size_t)(e2 & 0xffffu) * 64 + lane];
        unsigned int v3 = F[(size_t)(e3 & 0xffffu) * 64 + lane];
        float w0 = wdec(e0), w1 = wdec(e1), w2 = wdec(e2), w3 = wdec(e3);
        ax = fmaf(w0, bf_lo(v0), ax); ay = fmaf(w0, bf_hi(v0), ay);
        ax = fmaf(w1, bf_lo(v1), ax); ay = fmaf(w1, bf_hi(v1), ay);
        ax = fmaf(w2, bf_lo(v2), ax); ay = fmaf(w2, bf_hi(v2), ay);
        ax = fmaf(w3, bf_lo(v3), ax); ay = fmaf(w3, bf_hi(v3), ay);
        dw += w0 + w1 + w2 + w3;
    }
    for (; j < end; ++j) {
        unsigned int e0 = csr4[j];
        unsigned int v0 = F[(size_t)(e0 & 0xffffu) * 64 + lane];
        float w0 = wdec(e0);
        ax = fmaf(w0, bf_lo(v0), ax); ay = fmaf(w0, bf_hi(v0), ay);
        dw += w0;
    }
    float inv = dw > 0.f ? 1.f / dw : 0.f;
    float2 r; r.x = ax * inv; r.y = ay * inv;
    reinterpret_cast<float2*>(out)[(size_t)wid * 64 + lane] = r;
}

// ======================= fallback path (fp32, small ws) ====================
__global__ __launch_bounds__(256) void gc_hist(
    const int2* __restrict__ edges, int* __restrict__ counts)
{
    int e = blockIdx.x * 256 + threadIdx.x;
    if (e >= NE) return;
    int2 p = edges[e];
    atomicAdd(counts + p.x, 1);
    atomicAdd(counts + p.y, 1);
}

__global__ __launch_bounds__(1024) void gc_scan(
    const int* __restrict__ counts, int* __restrict__ row_start,
    int* __restrict__ cursor)
{
    const int CHUNK = (NN + 1023) / 1024;
    __shared__ int part[1024];
    int t = threadIdx.x;
    int lo = t * CHUNK, hi = min(lo + CHUNK, NN);
    int s = 0;
    for (int i = lo; i < hi; ++i) s += counts[i];
    part[t] = s;
    __syncthreads();
    for (int off = 1; off < 1024; off <<= 1) {
        int v = (t >= off) ? part[t - off] : 0;
        __syncthreads();
        part[t] += v;
        __syncthreads();
    }
    int run = part[t] - s;
    for (int i = lo; i < hi; ++i) {
        int c = counts[i];
        row_start[i] = run;
        cursor[i]    = run;
        run += c;
    }
    if (t == 1023) row_start[NN] = part[1023];
}

__global__ __launch_bounds__(256) void gc_fill8(
    const int2* __restrict__ edges, const float* __restrict__ wts,
    int* __restrict__ cursor, int2* __restrict__ csr)
{
    int e = blockIdx.x * 256 + threadIdx.x;
    if (e >= NE) return;
    int2 p = edges[e];
    int wb = __float_as_int(wts[e]);
    int pos = atomicAdd(cursor + p.y, 1);
    csr[pos] = make_int2(p.x, wb);
    pos = atomicAdd(cursor + p.x, 1);
    csr[pos] = make_int2(p.y, wb);
}

__global__ __launch_bounds__(256) void gc_gather_f32(
    const int* __restrict__ row_start, const int2* __restrict__ csr,
    const float* __restrict__ F, float* __restrict__ out)
{
    int wid  = (blockIdx.x * 256 + threadIdx.x) >> 6;
    int lane = threadIdx.x & 63;
    if (wid >= NN) return;
    int j   = row_start[wid];
    int end = row_start[wid + 1];
    const float2* F2 = reinterpret_cast<const float2*>(F);
    float ax = 0.f, ay = 0.f, dw = 0.f;
    for (; j < end; ++j) {
        int2  cw = csr[j];
        float w  = __int_as_float(cw.y);
        float2 xv = F2[(size_t)cw.x * 64 + lane];
        ax = fmaf(w, xv.x, ax);
        ay = fmaf(w, xv.y, ay);
        dw += w;
    }
    float inv = dw > 0.f ? 1.f / dw : 0.f;
    float2 r; r.x = ax * inv; r.y = ay * inv;
    reinterpret_cast<float2*>(out)[(size_t)wid * 64 + lane] = r;
}

__global__ __launch_bounds__(256) void gc_gemm_f32(
    const float* __restrict__ src, float* __restrict__ dst,
    const float* __restrict__ Wm)
{
    __shared__ float Ws[D * D];
    __shared__ float axs[16 * D];
    const int tid = threadIdx.x;
    const int col = tid & 127;
    const int ty  = tid >> 7;
    const int rbase = blockIdx.x * 16;

    const float4* W4  = reinterpret_cast<const float4*>(Wm);
    float4*       Ws4 = reinterpret_cast<float4*>(Ws);
    #pragma unroll
    for (int i = 0; i < 16; ++i) Ws4[tid + i * 256] = W4[tid + i * 256];

    const float4* A4   = reinterpret_cast<const float4*>(src + (size_t)rbase * D);
    float4*       axs4 = reinterpret_cast<float4*>(axs);
    #pragma unroll
    for (int i = 0; i < 2; ++i) axs4[tid + i * 256] = A4[tid + i * 256];
    __syncthreads();

    float acc[8];
    #pragma unroll
    for (int i = 0; i < 8; ++i) acc[i] = 0.f;

    for (int k = 0; k < D; ++k) {
        float wv = Ws[k * D + col];
        #pragma unroll
        for (int i = 0; i < 8; ++i)
            acc[i] = fmaf(axs[(ty * 8 + i) * D + k], wv, acc[i]);
    }

    #pragma unroll
    for (int i = 0; i < 8; ++i)
        dst[(size_t)(rbase + ty * 8 + i) * D + col] = acc[i];
}

extern "C" void kernel_launch(void* const* d_in, const int* in_sizes, int n_in,
                              void* d_out, int out_size, void* d_ws, size_t ws_size,
                              hipStream_t stream) {
    const float* X     = (const float*)d_in[0];
    const int2*  edges = (const int2*)d_in[1];
    const float* wts   = (const float*)d_in[2];
    const float* Wm    = (const float*)d_in[3];
    float* out = (float*)d_out;
    char*  ws  = (char*)d_ws;

    const int eblocks = (NE + 255) / 256;   // 3125

    if (ws_size >= NEED_A) {
        int* cnt8 = (int*)(ws + OFF_CNT8);
        int* row8 = (int*)(ws + OFF_ROW8);
        int* cur8 = (int*)(ws + OFF_CUR8);
        int* bsum = (int*)(ws + OFF_BSUM);
        unsigned int*   csr4 = (unsigned int*)(ws + OFF_CSR4);
        unsigned short* xw   = (unsigned short*)(ws + OFF_XW);

        hipMemsetAsync(cnt8, 0, NC * sizeof(int), stream);
        gc_hist8<<<eblocks, 256, 0, stream>>>(edges, cnt8);
        gc_scanA<<<NSB, 256, 0, stream>>>(cnt8, bsum);
        gc_scanB<<<1, 1024, 0, stream>>>(bsum);
        gc_scanC<<<NSB, 256, 0, stream>>>(cnt8, bsum, row8, cur8);
        gc_fill4<<<eblocks, 256, 0, stream>>>(edges, wts, cur8, csr4);
        gc_gemm_bf16<<<NN / 16, 256, 0, stream>>>(X, xw, Wm);
        gc_gather4<<<(NN * 64 + 255) / 256, 256, 0, stream>>>(
            row8, csr4, (const unsigned int*)xw, out);
    } else {
        int*  counts    = (int*) (ws + OFF_CNT);
        int*  row_start = (int*) (ws + OFF_ROW);
        int*  cursor    = (int*) (ws + OFF_CUR);
        int2* csr       = (int2*)(ws + OFF_CSR8);

        hipMemsetAsync(counts, 0, NN * sizeof(int), stream);
        gc_hist<<<eblocks, 256, 0, stream>>>(edges, counts);
        gc_scan<<<1, 1024, 0, stream>>>(counts, row_start, cursor);
        gc_fill8<<<eblocks, 256, 0, stream>>>(edges, wts, cursor, csr);
        gc_gather_f32<<<(NN * 64 + 255) / 256, 256, 0, stream>>>(row_start, csr, X, out);
        gc_gemm_f32<<<NN / 16, 256, 0, stream>>>(out, out, Wm);
    }
}

// Round 11
// 291.568 us; speedup vs baseline: 4.3162x; 1.1031x over previous
//
#include <hip/hip_runtime.h>
#include <hip/hip_fp16.h>

#define NN 50000
#define NE 800000
#define D  128
#define NB 391                 // node buckets of 128 (391*128 >= 50000)
#define NG 8                   // sub-slabs per bucket (append-rate groups)
#define CAP 768                // per-(bucket,g) slab capacity (mean 511, +11 sigma)

// ---- main-path ws layout (bytes). Slab = NB*NG*CAP*8 = 19,218,432 exactly.
// XW aliases the slab prefix (dead after gc_csr; stream-ordered).
#define OFF_SLAB  0            // int2[NB*NG*CAP]   19,218,432
#define OFF_XW    0            // ushort[NN*D]      12,800,000 (alias, later)
#define OFF_CSR4  19218432     // uint[2E]           6,400,000  -> 25,618,432
#define OFF_BCNT  25618432     // int[NB*NG]            12,512  -> 25,630,944
#define OFF_BBASE 25630944     // int[NB+1]              1,568  -> 25,632,512
#define OFF_ROW   25632512     // int[NN+1]            200,004  -> 25,832,516
#define NEED_A    25832516

// ---- fallback ws layout ----
#define OFF_CNT  0
#define OFF_ROWF 200704
#define OFF_CUR  401408
#define OFF_CSR8 602112        // int2[2E] 12.8 MB

__device__ __forceinline__ float bf_lo(unsigned int v) { return __uint_as_float(v << 16); }
__device__ __forceinline__ float bf_hi(unsigned int v) { return __uint_as_float(v & 0xffff0000u); }
__device__ __forceinline__ float wdec(unsigned int v) {
    return __half2float(__ushort_as_half((unsigned short)(v >> 16)));
}

// K1: bin directed edges into (bucket, g) slabs. High append rate per counter
// (mean 511) -> slab tail lines fill within a short window -> merged writebacks.
// Entry: .x = src(16b) | dst_local(7b)<<16 ; .y = weight fp32 bits.
__global__ __launch_bounds__(256) void gc_bin(
    const int2* __restrict__ edges, const float* __restrict__ wts,
    int* __restrict__ bcnt, int2* __restrict__ slab)
{
    int e = blockIdx.x * 256 + threadIdx.x;
    if (e >= NE) return;
    int g = blockIdx.x & (NG - 1);
    int2 p = edges[e];
    int wb = __float_as_int(wts[e]);
    {
        int b = p.y >> 7, dl = p.y & 127;
        int pos = atomicAdd(bcnt + b * NG + g, 1);
        if (pos < CAP)
            slab[((size_t)b * NG + g) * CAP + pos] = make_int2(p.x | (dl << 16), wb);
    }
    {
        int b = p.x >> 7, dl = p.x & 127;
        int pos = atomicAdd(bcnt + b * NG + g, 1);
        if (pos < CAP)
            slab[((size_t)b * NG + g) * CAP + pos] = make_int2(p.y | (dl << 16), wb);
    }
}

// K2: single tiny block: exclusive scan of per-bucket totals -> bbase[NB+1]
__global__ __launch_bounds__(1024) void gc_bscan(
    const int* __restrict__ bcnt, int* __restrict__ bbase)
{
    __shared__ int part[1024];
    int t = threadIdx.x;
    int tot = 0;
    if (t < NB) {
        #pragma unroll
        for (int g = 0; g < NG; ++g) tot += min(bcnt[t * NG + g], CAP);
    }
    part[t] = tot;
    __syncthreads();
    for (int off = 1; off < 1024; off <<= 1) {
        int v = (t >= off) ? part[t - off] : 0;
        __syncthreads();
        part[t] += v;
        __syncthreads();
    }
    if (t < NB) bbase[t] = part[t] - tot;   // exclusive
    if (t == NB - 1) bbase[NB] = part[t];   // total
}

// K3: per-bucket CSR build. Block b counts its entries (LDS), scans 128 local
// nodes, writes row_start, then scatters 4B entries into its private
// contiguous CSR region -> single-block short-window writes, fully merged.
__global__ __launch_bounds__(256) void gc_csr(
    const int* __restrict__ bcnt, const int2* __restrict__ slab,
    const int* __restrict__ bbase, int* __restrict__ row_start,
    unsigned int* __restrict__ csr4)
{
    __shared__ int ncnt[128], ncur[128], part[128];
    const int tid = threadIdx.x;
    const int b = blockIdx.x;

    if (tid < 128) ncnt[tid] = 0;
    __syncthreads();

    int cg[NG];
    #pragma unroll
    for (int g = 0; g < NG; ++g) cg[g] = min(bcnt[b * NG + g], CAP);

    // pass A: count per local node
    #pragma unroll
    for (int g = 0; g < NG; ++g) {
        const int2* s = slab + ((size_t)b * NG + g) * CAP;
        for (int j = tid; j < cg[g]; j += 256)
            atomicAdd(&ncnt[(s[j].x >> 16) & 127], 1);
    }
    __syncthreads();

    // local exclusive scan of 128 counts
    if (tid < 128) part[tid] = ncnt[tid];
    __syncthreads();
    for (int off = 1; off < 128; off <<= 1) {
        int v = 0;
        if (tid < 128 && tid >= off) v = part[tid - off];
        __syncthreads();
        if (tid < 128) part[tid] += v;
        __syncthreads();
    }
    int base = bbase[b];
    if (tid < 128) {
        int start = base + part[tid] - ncnt[tid];
        int n = b * 128 + tid;
        if (n < NN) row_start[n] = start;
        ncur[tid] = start;
    }
    if (b == 0 && tid == 0) row_start[NN] = bbase[NB];
    __syncthreads();

    // pass B: scatter into private CSR region (slab slice is L2-hot)
    #pragma unroll
    for (int g = 0; g < NG; ++g) {
        const int2* s = slab + ((size_t)b * NG + g) * CAP;
        for (int j = tid; j < cg[g]; j += 256) {
            int2 en = s[j];
            int dl = (en.x >> 16) & 127;
            unsigned int hb =
                (unsigned int)__half_as_ushort(__float2half_rn(__int_as_float(en.y))) << 16;
            int pos = atomicAdd(&ncur[dl], 1);
            csr4[pos] = (unsigned int)(en.x & 0xffff) | hb;
        }
    }
}

// K4: XW = X @ W, bf16 RNE output (packed). Runs AFTER gc_csr (XW aliases slab).
__global__ __launch_bounds__(256) void gc_gemm_bf16(
    const float* __restrict__ src, unsigned short* __restrict__ dst,
    const float* __restrict__ Wm)
{
    __shared__ float Ws[D * D];
    __shared__ float axs[16 * D];
    const int tid = threadIdx.x;
    const int col = tid & 127;
    const int ty  = tid >> 7;
    const int rbase = blockIdx.x * 16;

    const float4* W4  = reinterpret_cast<const float4*>(Wm);
    float4*       Ws4 = reinterpret_cast<float4*>(Ws);
    #pragma unroll
    for (int i = 0; i < 16; ++i) Ws4[tid + i * 256] = W4[tid + i * 256];

    const float4* A4   = reinterpret_cast<const float4*>(src + (size_t)rbase * D);
    float4*       axs4 = reinterpret_cast<float4*>(axs);
    #pragma unroll
    for (int i = 0; i < 2; ++i) axs4[tid + i * 256] = A4[tid + i * 256];
    __syncthreads();

    float acc[8];
    #pragma unroll
    for (int i = 0; i < 8; ++i) acc[i] = 0.f;

    for (int k = 0; k < D; ++k) {
        float wv = Ws[k * D + col];
        #pragma unroll
        for (int i = 0; i < 8; ++i)
            acc[i] = fmaf(axs[(ty * 8 + i) * D + k], wv, acc[i]);
    }

    #pragma unroll
    for (int i = 0; i < 8; ++i) {
        unsigned int bb = __float_as_uint(acc[i]);
        unsigned int r  = (bb + 0x7fffu + ((bb >> 16) & 1u)) >> 16;   // RNE
        dst[(size_t)(rbase + ty * 8 + i) * D + col] = (unsigned short)r;
    }
}

// K5: gather bf16 rows, fused degree + normalization -> out (final)
__global__ __launch_bounds__(256) void gc_gather4(
    const int* __restrict__ row_start, const unsigned int* __restrict__ csr4,
    const unsigned int* __restrict__ F, float* __restrict__ out)
{
    int wid  = (blockIdx.x * 256 + threadIdx.x) >> 6;
    int lane = threadIdx.x & 63;
    if (wid >= NN) return;
    int j   = row_start[wid];
    int end = row_start[wid + 1];
    float ax = 0.f, ay = 0.f, dw = 0.f;
    for (; j + 4 <= end; j += 4) {
        unsigned int e0 = csr4[j], e1 = csr4[j + 1];
        unsigned int e2 = csr4[j + 2], e3 = csr4[j + 3];
        unsigned int v0 = F[(size_t)(e0 & 0xffffu) * 64 + lane];
        unsigned int v1 = F[(size_t)(e1 & 0xffffu) * 64 + lane];
        unsigned int v2 = F[(size_t)(e2 & 0xffffu) * 64 + lane];
        unsigned int v3 = F[(size_t)(e3 & 0xffffu) * 64 + lane];
        float w0 = wdec(e0), w1 = wdec(e1), w2 = wdec(e2), w3 = wdec(e3);
        ax = fmaf(w0, bf_lo(v0), ax); ay = fmaf(w0, bf_hi(v0), ay);
        ax = fmaf(w1, bf_lo(v1), ax); ay = fmaf(w1, bf_hi(v1), ay);
        ax = fmaf(w2, bf_lo(v2), ax); ay = fmaf(w2, bf_hi(v2), ay);
        ax = fmaf(w3, bf_lo(v3), ax); ay = fmaf(w3, bf_hi(v3), ay);
        dw += w0 + w1 + w2 + w3;
    }
    for (; j < end; ++j) {
        unsigned int e0 = csr4[j];
        unsigned int v0 = F[(size_t)(e0 & 0xffffu) * 64 + lane];
        float w0 = wdec(e0);
        ax = fmaf(w0, bf_lo(v0), ax); ay = fmaf(w0, bf_hi(v0), ay);
        dw += w0;
    }
    float inv = dw > 0.f ? 1.f / dw : 0.f;
    float2 r; r.x = ax * inv; r.y = ay * inv;
    reinterpret_cast<float2*>(out)[(size_t)wid * 64 + lane] = r;
}

// ======================= fallback path (fp32, small ws) ====================
__global__ __launch_bounds__(256) void gc_hist(
    const int2* __restrict__ edges, int* __restrict__ counts)
{
    int e = blockIdx.x * 256 + threadIdx.x;
    if (e >= NE) return;
    int2 p = edges[e];
    atomicAdd(counts + p.x, 1);
    atomicAdd(counts + p.y, 1);
}

__global__ __launch_bounds__(1024) void gc_scan(
    const int* __restrict__ counts, int* __restrict__ row_start,
    int* __restrict__ cursor)
{
    const int CHUNK = (NN + 1023) / 1024;
    __shared__ int part[1024];
    int t = threadIdx.x;
    int lo = t * CHUNK, hi = min(lo + CHUNK, NN);
    int s = 0;
    for (int i = lo; i < hi; ++i) s += counts[i];
    part[t] = s;
    __syncthreads();
    for (int off = 1; off < 1024; off <<= 1) {
        int v = (t >= off) ? part[t - off] : 0;
        __syncthreads();
        part[t] += v;
        __syncthreads();
    }
    int run = part[t] - s;
    for (int i = lo; i < hi; ++i) {
        int c = counts[i];
        row_start[i] = run;
        cursor[i]    = run;
        run += c;
    }
    if (t == 1023) row_start[NN] = part[1023];
}

__global__ __launch_bounds__(256) void gc_fill8(
    const int2* __restrict__ edges, const float* __restrict__ wts,
    int* __restrict__ cursor, int2* __restrict__ csr)
{
    int e = blockIdx.x * 256 + threadIdx.x;
    if (e >= NE) return;
    int2 p = edges[e];
    int wb = __float_as_int(wts[e]);
    int pos = atomicAdd(cursor + p.y, 1);
    csr[pos] = make_int2(p.x, wb);
    pos = atomicAdd(cursor + p.x, 1);
    csr[pos] = make_int2(p.y, wb);
}

__global__ __launch_bounds__(256) void gc_gather_f32(
    const int* __restrict__ row_start, const int2* __restrict__ csr,
    const float* __restrict__ F, float* __restrict__ out)
{
    int wid  = (blockIdx.x * 256 + threadIdx.x) >> 6;
    int lane = threadIdx.x & 63;
    if (wid >= NN) return;
    int j   = row_start[wid];
    int end = row_start[wid + 1];
    const float2* F2 = reinterpret_cast<const float2*>(F);
    float ax = 0.f, ay = 0.f, dw = 0.f;
    for (; j < end; ++j) {
        int2  cw = csr[j];
        float w  = __int_as_float(cw.y);
        float2 xv = F2[(size_t)cw.x * 64 + lane];
        ax = fmaf(w, xv.x, ax);
        ay = fmaf(w, xv.y, ay);
        dw += w;
    }
    float inv = dw > 0.f ? 1.f / dw : 0.f;
    float2 r; r.x = ax * inv; r.y = ay * inv;
    reinterpret_cast<float2*>(out)[(size_t)wid * 64 + lane] = r;
}

__global__ __launch_bounds__(256) void gc_gemm_f32(
    const float* __restrict__ src, float* __restrict__ dst,
    const float* __restrict__ Wm)
{
    __shared__ float Ws[D * D];
    __shared__ float axs[16 * D];
    const int tid = threadIdx.x;
    const int col = tid & 127;
    const int ty  = tid >> 7;
    const int rbase = blockIdx.x * 16;

    const float4* W4  = reinterpret_cast<const float4*>(Wm);
    float4*       Ws4 = reinterpret_cast<float4*>(Ws);
    #pragma unroll
    for (int i = 0; i < 16; ++i) Ws4[tid + i * 256] = W4[tid + i * 256];

    const float4* A4   = reinterpret_cast<const float4*>(src + (size_t)rbase * D);
    float4*       axs4 = reinterpret_cast<float4*>(axs);
    #pragma unroll
    for (int i = 0; i < 2; ++i) axs4[tid + i * 256] = A4[tid + i * 256];
    __syncthreads();

    float acc[8];
    #pragma unroll
    for (int i = 0; i < 8; ++i) acc[i] = 0.f;

    for (int k = 0; k < D; ++k) {
        float wv = Ws[k * D + col];
        #pragma unroll
        for (int i = 0; i < 8; ++i)
            acc[i] = fmaf(axs[(ty * 8 + i) * D + k], wv, acc[i]);
    }

    #pragma unroll
    for (int i = 0; i < 8; ++i)
        dst[(size_t)(rbase + ty * 8 + i) * D + col] = acc[i];
}

extern "C" void kernel_launch(void* const* d_in, const int* in_sizes, int n_in,
                              void* d_out, int out_size, void* d_ws, size_t ws_size,
                              hipStream_t stream) {
    const float* X     = (const float*)d_in[0];
    const int2*  edges = (const int2*)d_in[1];
    const float* wts   = (const float*)d_in[2];
    const float* Wm    = (const float*)d_in[3];
    float* out = (float*)d_out;
    char*  ws  = (char*)d_ws;

    const int eblocks = (NE + 255) / 256;   // 3125

    if (ws_size >= NEED_A) {
        int2* slab = (int2*)(ws + OFF_SLAB);
        unsigned int*   csr4 = (unsigned int*)(ws + OFF_CSR4);
        int*  bcnt  = (int*)(ws + OFF_BCNT);
        int*  bbase = (int*)(ws + OFF_BBASE);
        int*  row   = (int*)(ws + OFF_ROW);
        unsigned short* xw = (unsigned short*)(ws + OFF_XW);   // aliases slab

        hipMemsetAsync(bcnt, 0, NB * NG * sizeof(int), stream);
        gc_bin<<<eblocks, 256, 0, stream>>>(edges, wts, bcnt, slab);
        gc_bscan<<<1, 1024, 0, stream>>>(bcnt, bbase);
        gc_csr<<<NB, 256, 0, stream>>>(bcnt, slab, bbase, row, csr4);
        gc_gemm_bf16<<<NN / 16, 256, 0, stream>>>(X, xw, Wm);   // overwrites slab
        gc_gather4<<<(NN * 64 + 255) / 256, 256, 0, stream>>>(
            row, csr4, (const unsigned int*)xw, out);
    } else {
        int*  counts    = (int*) (ws + OFF_CNT);
        int*  row_start = (int*) (ws + OFF_ROWF);
        int*  cursor    = (int*) (ws + OFF_CUR);
        int2* csr       = (int2*)(ws + OFF_CSR8);

        hipMemsetAsync(counts, 0, NN * sizeof(int), stream);
        gc_hist<<<eblocks, 256, 0, stream>>>(edges, counts);
        gc_scan<<<1, 1024, 0, stream>>>(counts, row_start, cursor);
        gc_fill8<<<eblocks, 256, 0, stream>>>(edges, wts, cursor, csr);
        gc_gather_f32<<<(NN * 64 + 255) / 256, 256, 0, stream>>>(row_start, csr, X, out);
        gc_gemm_f32<<<NN / 16, 256, 0, stream>>>(out, out, Wm);
    }
}

// Round 12
// 156.738 us; speedup vs baseline: 8.0292x; 1.8602x over previous
//
#include <hip/hip_runtime.h>
#include <hip/hip_fp16.h>

#define NN 50000
#define NE 800000
#define D  128
#define NB 391                 // node buckets of 128 (391*128 >= 50000)
#define NS 256                 // sorter blocks
#define EPS 3125               // edges per sorter (NS*EPS == NE exactly)
#define SN (NB * NS)           // 100096 scan elements
#define SCB 1024
#define NSB ((SN + SCB - 1) / SCB)   // 98

// ---- main-path ws layout (bytes) ----
#define OFF_SLAB 0             // int2[2E]      12,800,000
#define OFF_XW   0             // ushort[NN*D]  12,800,000 (alias; slab dead after gc_csr)
#define OFF_CSR4 12800000      // uint[2E]       6,400,000
#define OFF_HIST 19200000      // int[SN]          400,384
#define OFF_BASE 19600384      // int[SN]          400,384
#define OFF_BSUM 20000768      // int[NSB]             512 (padded)
#define OFF_ROW  20001280      // int[NN+1]        200,004
#define NEED_A   20201284

// ---- fallback ws layout ----
#define OFF_CNT  0
#define OFF_ROWF 200704
#define OFF_CUR  401408
#define OFF_CSR8 602112        // int2[2E] 12.8 MB

__device__ __forceinline__ float bf_lo(unsigned int v) { return __uint_as_float(v << 16); }
__device__ __forceinline__ float bf_hi(unsigned int v) { return __uint_as_float(v & 0xffff0000u); }
__device__ __forceinline__ float wdec(unsigned int v) {
    return __half2float(__ushort_as_half((unsigned short)(v >> 16)));
}

// K1: per-sorter histogram over 391 buckets (LDS), written b-major: histT[b*NS+s]
__global__ __launch_bounds__(256) void gc_shist(
    const int2* __restrict__ edges, int* __restrict__ histT)
{
    __shared__ int h[NB];
    const int s = blockIdx.x;
    for (int i = threadIdx.x; i < NB; i += 256) h[i] = 0;
    __syncthreads();
    const int e0 = s * EPS;
    for (int i = threadIdx.x; i < EPS; i += 256) {
        int2 p = edges[e0 + i];
        atomicAdd(&h[p.y >> 7], 1);
        atomicAdd(&h[p.x >> 7], 1);
    }
    __syncthreads();
    for (int b = threadIdx.x; b < NB; b += 256) histT[b * NS + s] = h[b];
}

// K2a: per-chunk partial sums
__global__ __launch_bounds__(256) void gc_scanA(
    const int* __restrict__ in, int* __restrict__ bsum)
{
    __shared__ int red[256];
    int base = blockIdx.x * SCB;
    int s = 0;
    for (int i = threadIdx.x; i < SCB; i += 256) {
        int idx = base + i;
        s += (idx < SN) ? in[idx] : 0;
    }
    red[threadIdx.x] = s;
    __syncthreads();
    for (int off = 128; off > 0; off >>= 1) {
        if (threadIdx.x < off) red[threadIdx.x] += red[threadIdx.x + off];
        __syncthreads();
    }
    if (threadIdx.x == 0) bsum[blockIdx.x] = red[0];
}

// K2b: single-block exclusive scan of NSB block sums
__global__ __launch_bounds__(1024) void gc_scanB(int* __restrict__ bsum)
{
    __shared__ int part[1024];
    int t = threadIdx.x;
    int v = (t < NSB) ? bsum[t] : 0;
    part[t] = v;
    __syncthreads();
    for (int off = 1; off < 1024; off <<= 1) {
        int x = (t >= off) ? part[t - off] : 0;
        __syncthreads();
        part[t] += x;
        __syncthreads();
    }
    if (t < NSB) bsum[t] = part[t] - v;
}

// K2c: per-chunk local exclusive scan + block offset -> baseT
__global__ __launch_bounds__(256) void gc_scanC(
    const int* __restrict__ in, const int* __restrict__ bsum,
    int* __restrict__ baseT)
{
    __shared__ int part[256];
    int base = blockIdx.x * SCB;
    int idx0 = base + threadIdx.x * 4;
    int4 v = make_int4(0, 0, 0, 0);
    if (idx0 + 3 < SN) v = *reinterpret_cast<const int4*>(in + idx0);
    int s = v.x + v.y + v.z + v.w;
    part[threadIdx.x] = s;
    __syncthreads();
    for (int off = 1; off < 256; off <<= 1) {
        int x = (threadIdx.x >= off) ? part[threadIdx.x - off] : 0;
        __syncthreads();
        part[threadIdx.x] += x;
        __syncthreads();
    }
    int run = bsum[blockIdx.x] + part[threadIdx.x] - s;
    if (idx0 + 3 < SN)
        *reinterpret_cast<int4*>(baseT + idx0) =
            make_int4(run, run + v.x, run + v.x + v.y, run + v.x + v.y + v.z);
}

// K3: scatter entries into per-(sorter,bucket) contiguous chunks (no global atomics)
// Entry: .x = src(16b) | dst_local(7b)<<16 ; .y = weight fp32 bits.
__global__ __launch_bounds__(256) void gc_sscat(
    const int2* __restrict__ edges, const float* __restrict__ wts,
    const int* __restrict__ baseT, int2* __restrict__ slab)
{
    __shared__ int cur[NB];
    const int s = blockIdx.x;
    for (int b = threadIdx.x; b < NB; b += 256) cur[b] = baseT[b * NS + s];
    __syncthreads();
    const int e0 = s * EPS;
    for (int i = threadIdx.x; i < EPS; i += 256) {
        int2 p = edges[e0 + i];
        int wb = __float_as_int(wts[e0 + i]);
        int b = p.y >> 7;
        int pos = atomicAdd(&cur[b], 1);
        slab[pos] = make_int2(p.x | ((p.y & 127) << 16), wb);
        b = p.x >> 7;
        pos = atomicAdd(&cur[b], 1);
        slab[pos] = make_int2(p.y | ((p.x & 127) << 16), wb);
    }
}

// K4: per-bucket CSR build from the contiguous bucket region
__global__ __launch_bounds__(256) void gc_csr(
    const int* __restrict__ baseT, const int2* __restrict__ slab,
    int* __restrict__ row_start, unsigned int* __restrict__ csr4)
{
    __shared__ int ncnt[128], ncur[128], part[128];
    const int tid = threadIdx.x;
    const int b = blockIdx.x;
    const int start = baseT[b * NS];
    const int end = (b == NB - 1) ? (2 * NE) : baseT[(b + 1) * NS];

    if (tid < 128) ncnt[tid] = 0;
    __syncthreads();

    for (int j = start + tid; j < end; j += 256)
        atomicAdd(&ncnt[(slab[j].x >> 16) & 127], 1);
    __syncthreads();

    if (tid < 128) part[tid] = ncnt[tid];
    __syncthreads();
    for (int off = 1; off < 128; off <<= 1) {
        int v = 0;
        if (tid < 128 && tid >= off) v = part[tid - off];
        __syncthreads();
        if (tid < 128) part[tid] += v;
        __syncthreads();
    }
    if (tid < 128) {
        int st = start + part[tid] - ncnt[tid];
        int n = b * 128 + tid;
        if (n < NN) row_start[n] = st;
        ncur[tid] = st;
    }
    if (b == 0 && tid == 0) row_start[NN] = 2 * NE;
    __syncthreads();

    for (int j = start + tid; j < end; j += 256) {
        int2 en = slab[j];
        int dl = (en.x >> 16) & 127;
        unsigned int hb =
            (unsigned int)__half_as_ushort(__float2half_rn(__int_as_float(en.y))) << 16;
        int pos = atomicAdd(&ncur[dl], 1);
        csr4[pos] = (unsigned int)(en.x & 0xffff) | hb;
    }
}

// K5: XW = X @ W, bf16 RNE output. Runs AFTER gc_csr (XW aliases slab).
__global__ __launch_bounds__(256) void gc_gemm_bf16(
    const float* __restrict__ src, unsigned short* __restrict__ dst,
    const float* __restrict__ Wm)
{
    __shared__ float Ws[D * D];
    __shared__ float axs[16 * D];
    const int tid = threadIdx.x;
    const int col = tid & 127;
    const int ty  = tid >> 7;
    const int rbase = blockIdx.x * 16;

    const float4* W4  = reinterpret_cast<const float4*>(Wm);
    float4*       Ws4 = reinterpret_cast<float4*>(Ws);
    #pragma unroll
    for (int i = 0; i < 16; ++i) Ws4[tid + i * 256] = W4[tid + i * 256];

    const float4* A4   = reinterpret_cast<const float4*>(src + (size_t)rbase * D);
    float4*       axs4 = reinterpret_cast<float4*>(axs);
    #pragma unroll
    for (int i = 0; i < 2; ++i) axs4[tid + i * 256] = A4[tid + i * 256];
    __syncthreads();

    float acc[8];
    #pragma unroll
    for (int i = 0; i < 8; ++i) acc[i] = 0.f;

    for (int k = 0; k < D; ++k) {
        float wv = Ws[k * D + col];
        #pragma unroll
        for (int i = 0; i < 8; ++i)
            acc[i] = fmaf(axs[(ty * 8 + i) * D + k], wv, acc[i]);
    }

    #pragma unroll
    for (int i = 0; i < 8; ++i) {
        unsigned int bb = __float_as_uint(acc[i]);
        unsigned int r  = (bb + 0x7fffu + ((bb >> 16) & 1u)) >> 16;   // RNE
        dst[(size_t)(rbase + ty * 8 + i) * D + col] = (unsigned short)r;
    }
}

// K6: gather bf16 rows, fused degree + normalization -> out (final)
__global__ __launch_bounds__(256) void gc_gather4(
    const int* __restrict__ row_start, const unsigned int* __restrict__ csr4,
    const unsigned int* __restrict__ F, float* __restrict__ out)
{
    int wid  = (blockIdx.x * 256 + threadIdx.x) >> 6;
    int lane = threadIdx.x & 63;
    if (wid >= NN) return;
    int j   = row_start[wid];
    int end = row_start[wid + 1];
    float ax = 0.f, ay = 0.f, dw = 0.f;
    for (; j + 4 <= end; j += 4) {
        unsigned int e0 = csr4[j], e1 = csr4[j + 1];
        unsigned int e2 = csr4[j + 2], e3 = csr4[j + 3];
        unsigned int v0 = F[(size_t)(e0 & 0xffffu) * 64 + lane];
        unsigned int v1 = F[(size_t)(e1 & 0xffffu) * 64 + lane];
        unsigned int v2 = F[(size_t)(e2 & 0xffffu) * 64 + lane];
        unsigned int v3 = F[(size_t)(e3 & 0xffffu) * 64 + lane];
        float w0 = wdec(e0), w1 = wdec(e1), w2 = wdec(e2), w3 = wdec(e3);
        ax = fmaf(w0, bf_lo(v0), ax); ay = fmaf(w0, bf_hi(v0), ay);
        ax = fmaf(w1, bf_lo(v1), ax); ay = fmaf(w1, bf_hi(v1), ay);
        ax = fmaf(w2, bf_lo(v2), ax); ay = fmaf(w2, bf_hi(v2), ay);
        ax = fmaf(w3, bf_lo(v3), ax); ay = fmaf(w3, bf_hi(v3), ay);
        dw += w0 + w1 + w2 + w3;
    }
    for (; j < end; ++j) {
        unsigned int e0 = csr4[j];
        unsigned int v0 = F[(size_t)(e0 & 0xffffu) * 64 + lane];
        float w0 = wdec(e0);
        ax = fmaf(w0, bf_lo(v0), ax); ay = fmaf(w0, bf_hi(v0), ay);
        dw += w0;
    }
    float inv = dw > 0.f ? 1.f / dw : 0.f;
    float2 r; r.x = ax * inv; r.y = ay * inv;
    reinterpret_cast<float2*>(out)[(size_t)wid * 64 + lane] = r;
}

// ======================= fallback path (fp32, small ws) ====================
__global__ __launch_bounds__(256) void gc_hist(
    const int2* __restrict__ edges, int* __restrict__ counts)
{
    int e = blockIdx.x * 256 + threadIdx.x;
    if (e >= NE) return;
    int2 p = edges[e];
    atomicAdd(counts + p.x, 1);
    atomicAdd(counts + p.y, 1);
}

__global__ __launch_bounds__(1024) void gc_scan(
    const int* __restrict__ counts, int* __restrict__ row_start,
    int* __restrict__ cursor)
{
    const int CHUNK = (NN + 1023) / 1024;
    __shared__ int part[1024];
    int t = threadIdx.x;
    int lo = t * CHUNK, hi = min(lo + CHUNK, NN);
    int s = 0;
    for (int i = lo; i < hi; ++i) s += counts[i];
    part[t] = s;
    __syncthreads();
    for (int off = 1; off < 1024; off <<= 1) {
        int v = (t >= off) ? part[t - off] : 0;
        __syncthreads();
        part[t] += v;
        __syncthreads();
    }
    int run = part[t] - s;
    for (int i = lo; i < hi; ++i) {
        int c = counts[i];
        row_start[i] = run;
        cursor[i]    = run;
        run += c;
    }
    if (t == 1023) row_start[NN] = part[1023];
}

__global__ __launch_bounds__(256) void gc_fill8(
    const int2* __restrict__ edges, const float* __restrict__ wts,
    int* __restrict__ cursor, int2* __restrict__ csr)
{
    int e = blockIdx.x * 256 + threadIdx.x;
    if (e >= NE) return;
    int2 p = edges[e];
    int wb = __float_as_int(wts[e]);
    int pos = atomicAdd(cursor + p.y, 1);
    csr[pos] = make_int2(p.x, wb);
    pos = atomicAdd(cursor + p.x, 1);
    csr[pos] = make_int2(p.y, wb);
}

__global__ __launch_bounds__(256) void gc_gather_f32(
    const int* __restrict__ row_start, const int2* __restrict__ csr,
    const float* __restrict__ F, float* __restrict__ out)
{
    int wid  = (blockIdx.x * 256 + threadIdx.x) >> 6;
    int lane = threadIdx.x & 63;
    if (wid >= NN) return;
    int j   = row_start[wid];
    int end = row_start[wid + 1];
    const float2* F2 = reinterpret_cast<const float2*>(F);
    float ax = 0.f, ay = 0.f, dw = 0.f;
    for (; j < end; ++j) {
        int2  cw = csr[j];
        float w  = __int_as_float(cw.y);
        float2 xv = F2[(size_t)cw.x * 64 + lane];
        ax = fmaf(w, xv.x, ax);
        ay = fmaf(w, xv.y, ay);
        dw += w;
    }
    float inv = dw > 0.f ? 1.f / dw : 0.f;
    float2 r; r.x = ax * inv; r.y = ay * inv;
    reinterpret_cast<float2*>(out)[(size_t)wid * 64 + lane] = r;
}

__global__ __launch_bounds__(256) void gc_gemm_f32(
    const float* __restrict__ src, float* __restrict__ dst,
    const float* __restrict__ Wm)
{
    __shared__ float Ws[D * D];
    __shared__ float axs[16 * D];
    const int tid = threadIdx.x;
    const int col = tid & 127;
    const int ty  = tid >> 7;
    const int rbase = blockIdx.x * 16;

    const float4* W4  = reinterpret_cast<const float4*>(Wm);
    float4*       Ws4 = reinterpret_cast<float4*>(Ws);
    #pragma unroll
    for (int i = 0; i < 16; ++i) Ws4[tid + i * 256] = W4[tid + i * 256];

    const float4* A4   = reinterpret_cast<const float4*>(src + (size_t)rbase * D);
    float4*       axs4 = reinterpret_cast<float4*>(axs);
    #pragma unroll
    for (int i = 0; i < 2; ++i) axs4[tid + i * 256] = A4[tid + i * 256];
    __syncthreads();

    float acc[8];
    #pragma unroll
    for (int i = 0; i < 8; ++i) acc[i] = 0.f;

    for (int k = 0; k < D; ++k) {
        float wv = Ws[k * D + col];
        #pragma unroll
        for (int i = 0; i < 8; ++i)
            acc[i] = fmaf(axs[(ty * 8 + i) * D + k], wv, acc[i]);
    }

    #pragma unroll
    for (int i = 0; i < 8; ++i)
        dst[(size_t)(rbase + ty * 8 + i) * D + col] = acc[i];
}

extern "C" void kernel_launch(void* const* d_in, const int* in_sizes, int n_in,
                              void* d_out, int out_size, void* d_ws, size_t ws_size,
                              hipStream_t stream) {
    const float* X     = (const float*)d_in[0];
    const int2*  edges = (const int2*)d_in[1];
    const float* wts   = (const float*)d_in[2];
    const float* Wm    = (const float*)d_in[3];
    float* out = (float*)d_out;
    char*  ws  = (char*)d_ws;

    const int eblocks = (NE + 255) / 256;   // 3125

    if (ws_size >= NEED_A) {
        int2* slab  = (int2*)(ws + OFF_SLAB);
        unsigned int* csr4 = (unsigned int*)(ws + OFF_CSR4);
        int*  histT = (int*)(ws + OFF_HIST);
        int*  baseT = (int*)(ws + OFF_BASE);
        int*  bsum  = (int*)(ws + OFF_BSUM);
        int*  row   = (int*)(ws + OFF_ROW);
        unsigned short* xw = (unsigned short*)(ws + OFF_XW);   // aliases slab

        gc_shist<<<NS, 256, 0, stream>>>(edges, histT);
        gc_scanA<<<NSB, 256, 0, stream>>>(histT, bsum);
        gc_scanB<<<1, 1024, 0, stream>>>(bsum);
        gc_scanC<<<NSB, 256, 0, stream>>>(histT, bsum, baseT);
        gc_sscat<<<NS, 256, 0, stream>>>(edges, wts, baseT, slab);
        gc_csr<<<NB, 256, 0, stream>>>(baseT, slab, row, csr4);
        gc_gemm_bf16<<<NN / 16, 256, 0, stream>>>(X, xw, Wm);   // overwrites slab
        gc_gather4<<<(NN * 64 + 255) / 256, 256, 0, stream>>>(
            row, csr4, (const unsigned int*)xw, out);
    } else {
        int*  counts    = (int*) (ws + OFF_CNT);
        int*  row_start = (int*) (ws + OFF_ROWF);
        int*  cursor    = (int*) (ws + OFF_CUR);
        int2* csr       = (int2*)(ws + OFF_CSR8);

        hipMemsetAsync(counts, 0, NN * sizeof(int), stream);
        gc_hist<<<eblocks, 256, 0, stream>>>(edges, counts);
        gc_scan<<<1, 1024, 0, stream>>>(counts, row_start, cursor);
        gc_fill8<<<eblocks, 256, 0, stream>>>(edges, wts, cursor, csr);
        gc_gather_f32<<<(NN * 64 + 255) / 256, 256, 0, stream>>>(row_start, csr, X, out);
        gc_gemm_f32<<<NN / 16, 256, 0, stream>>>(out, out, Wm);
    }
}